// Round 1
// baseline (622.835 us; speedup 1.0000x reference)
//
#include <hip/hip_runtime.h>
#include <hip/hip_bf16.h>
#include <math.h>

#define N_NODES   100000
#define N_EDGES   1600000
#define D_FEAT    128
#define N_CLASSES 64

// ---------------------------------------------------------------------------
// K1: deg[i] = 1  (self-loop)
// ---------------------------------------------------------------------------
__global__ __launch_bounds__(256) void init_deg_kernel(int* __restrict__ deg) {
    int i = blockIdx.x * 256 + threadIdx.x;
    if (i < N_NODES) deg[i] = 1;
}

// ---------------------------------------------------------------------------
// K2: deg[dst[e]] += 1 for each edge
// ---------------------------------------------------------------------------
__global__ __launch_bounds__(256) void count_deg_kernel(const int* __restrict__ dst,
                                                        int* __restrict__ deg) {
    int e = blockIdx.x * 256 + threadIdx.x;
    if (e < N_EDGES) atomicAdd(&deg[dst[e]], 1);
}

// ---------------------------------------------------------------------------
// K3: z'[i][c] = dinv[i] * sum_k x[i][k] * W[c][k]
//     writes z' to ws, and initializes out with the self-loop term (= z').
//     Block: 256 threads = 4 waves. Each thread: class c = tid&63, 4 rows.
//     Block covers 16 rows. W staged in LDS with +1 padding (129 floats/row):
//     main-loop read Ws[c*129 + k] -> bank (c+k)%32 -> 2-way alias (free).
// ---------------------------------------------------------------------------
__global__ __launch_bounds__(256) void gemm_kernel(const float* __restrict__ x,
                                                   const float* __restrict__ W,
                                                   const int* __restrict__ deg,
                                                   float* __restrict__ zp,
                                                   float* __restrict__ out) {
    __shared__ float Ws[N_CLASSES * 129];
    const int tid = threadIdx.x;

    // Stage W: consecutive tid -> consecutive flat W index (coalesced global),
    // LDS addresses c*129 + k (k consecutive within lane-group) -> conflict-free.
    for (int i = tid; i < N_CLASSES * D_FEAT; i += 256) {
        int c = i >> 7;       // /128
        int k = i & 127;
        Ws[c * 129 + k] = W[i];
    }
    __syncthreads();

    const int w = tid >> 6;     // wave id 0..3
    const int c = tid & 63;     // class
    const int rbase = blockIdx.x * 16;

    int rows[4];
#pragma unroll
    for (int i = 0; i < 4; i++) rows[i] = rbase + w + 4 * i;

    float acc[4] = {0.f, 0.f, 0.f, 0.f};
    const float4* __restrict__ x4 = (const float4*)x;

    for (int k4 = 0; k4 < D_FEAT / 4; k4++) {
        float4 xv[4];
#pragma unroll
        for (int i = 0; i < 4; i++) xv[i] = x4[rows[i] * (D_FEAT / 4) + k4];
        const int kb = k4 * 4;
        float w0 = Ws[c * 129 + kb + 0];
        float w1 = Ws[c * 129 + kb + 1];
        float w2 = Ws[c * 129 + kb + 2];
        float w3 = Ws[c * 129 + kb + 3];
#pragma unroll
        for (int i = 0; i < 4; i++) {
            acc[i] += xv[i].x * w0;
            acc[i] += xv[i].y * w1;
            acc[i] += xv[i].z * w2;
            acc[i] += xv[i].w * w3;
        }
    }

#pragma unroll
    for (int i = 0; i < 4; i++) {
        const int r = rows[i];
        const float dinv = rsqrtf((float)deg[r]);
        const float z = acc[i] * dinv;       // z' = z * dinv[row]
        zp[r * N_CLASSES + c]  = z;
        out[r * N_CLASSES + c] = z;          // self-loop init of accumulator
    }
}

// ---------------------------------------------------------------------------
// K4: for each edge e: out[dst[e]][c] += z'[src[e]][c]
//     One wave per edge; lanes = classes. Gather is a coalesced 256B row read.
// ---------------------------------------------------------------------------
__global__ __launch_bounds__(256) void scatter_kernel(const int* __restrict__ src,
                                                      const int* __restrict__ dst,
                                                      const float* __restrict__ zp,
                                                      float* __restrict__ out) {
    const int idx = blockIdx.x * 256 + threadIdx.x;
    const int e = idx >> 6;
    const int c = idx & 63;
    const int s = src[e];
    const int d = dst[e];
    const float v = zp[s * N_CLASSES + c];
    atomicAdd(&out[d * N_CLASSES + c], v);
}

// ---------------------------------------------------------------------------
// K5: out[i][:] = log_softmax(dinv[i]*out[i][:] + b[:])
//     One wave per node; 64 lanes = 64 classes; shuffle reductions.
// ---------------------------------------------------------------------------
__global__ __launch_bounds__(256) void softmax_kernel(const int* __restrict__ deg,
                                                      const float* __restrict__ b,
                                                      float* __restrict__ out) {
    const int idx = blockIdx.x * 256 + threadIdx.x;
    const int i = idx >> 6;
    const int c = idx & 63;
    const float dinv = rsqrtf((float)deg[i]);
    float v = out[idx] * dinv + b[c];

    float m = v;
#pragma unroll
    for (int off = 32; off > 0; off >>= 1)
        m = fmaxf(m, __shfl_xor(m, off, 64));

    float ex = __expf(v - m);
    float l = ex;
#pragma unroll
    for (int off = 32; off > 0; off >>= 1)
        l += __shfl_xor(l, off, 64);

    out[idx] = v - m - __logf(l);
}

// ---------------------------------------------------------------------------
// Launch
// ---------------------------------------------------------------------------
extern "C" void kernel_launch(void* const* d_in, const int* in_sizes, int n_in,
                              void* d_out, int out_size, void* d_ws, size_t ws_size,
                              hipStream_t stream) {
    const float* x    = (const float*)d_in[0];
    const int*   edge = (const int*)d_in[1];   // [2, E]: first E = src, next E = dst
    const float* W    = (const float*)d_in[2];
    const float* b    = (const float*)d_in[3];
    float* out = (float*)d_out;

    // ws layout: deg (N ints) at 0; z' (N*64 floats) at 4 MiB offset.
    int*   deg = (int*)d_ws;
    float* zp  = (float*)((char*)d_ws + (4u << 20));

    const int* srcv = edge;
    const int* dstv = edge + N_EDGES;

    init_deg_kernel<<<(N_NODES + 255) / 256, 256, 0, stream>>>(deg);
    count_deg_kernel<<<(N_EDGES + 255) / 256, 256, 0, stream>>>(dstv, deg);
    gemm_kernel<<<N_NODES / 16, 256, 0, stream>>>(x, W, deg, zp, out);
    scatter_kernel<<<(N_EDGES * 64) / 256, 256, 0, stream>>>(srcv, dstv, zp, out);
    softmax_kernel<<<(N_NODES * 64) / 256, 256, 0, stream>>>(deg, b, out);
}

// Round 2
// 403.196 us; speedup vs baseline: 1.5447x; 1.5447x over previous
//
#include <hip/hip_runtime.h>
#include <hip/hip_bf16.h>
#include <math.h>

#define N_NODES   100000
#define N_EDGES   1600000
#define D_FEAT    128
#define N_CLASSES 64
#define NB_SCAN   98          // ceil(N_NODES / 1024)

// ---------------------------------------------------------------------------
// K1: deg[i] = 1  (self-loop)
// ---------------------------------------------------------------------------
__global__ __launch_bounds__(256) void init_deg_kernel(int* __restrict__ deg) {
    int i = blockIdx.x * 256 + threadIdx.x;
    if (i < N_NODES) deg[i] = 1;
}

// ---------------------------------------------------------------------------
// K2: deg[dst[e]] += 1  (in-degree histogram)
// ---------------------------------------------------------------------------
__global__ __launch_bounds__(256) void count_deg_kernel(const int* __restrict__ dst,
                                                        int* __restrict__ deg) {
    int e = blockIdx.x * 256 + threadIdx.x;
    if (e < N_EDGES) atomicAdd(&deg[dst[e]], 1);
}

// ---------------------------------------------------------------------------
// K3: per-block exclusive scan of cnt[i] = deg[i]-1 (incoming edge counts).
//     local[i] = exclusive scan within block; blksum[b] = block total.
// ---------------------------------------------------------------------------
__global__ __launch_bounds__(1024) void scan_block_kernel(const int* __restrict__ deg,
                                                          int* __restrict__ local,
                                                          int* __restrict__ blksum) {
    __shared__ int wsum[16];
    const int tid  = threadIdx.x;
    const int gid  = blockIdx.x * 1024 + tid;
    const int lane = tid & 63;
    const int wid  = tid >> 6;
    int v = (gid < N_NODES) ? (deg[gid] - 1) : 0;
    int s = v;   // inclusive scan within wave
#pragma unroll
    for (int off = 1; off < 64; off <<= 1) {
        int t = __shfl_up(s, off, 64);
        if (lane >= off) s += t;
    }
    if (lane == 63) wsum[wid] = s;
    __syncthreads();
    if (wid == 0) {
        int wv = (lane < 16) ? wsum[lane] : 0;
        int t2 = wv;
#pragma unroll
        for (int off = 1; off < 16; off <<= 1) {
            int t = __shfl_up(t2, off, 64);
            if (lane >= off) t2 += t;
        }
        if (lane < 16) wsum[lane] = t2 - wv;        // exclusive wave offsets
        if (lane == 15) blksum[blockIdx.x] = t2;    // block total
    }
    __syncthreads();
    if (gid < N_NODES) local[gid] = (s - v) + wsum[wid];
}

// ---------------------------------------------------------------------------
// K4: exclusive scan of the 98 block sums (in place), one 128-thread block.
// ---------------------------------------------------------------------------
__global__ __launch_bounds__(128) void scan_tops_kernel(int* __restrict__ blksum) {
    __shared__ int w0sum;
    const int tid  = threadIdx.x;
    const int lane = tid & 63;
    const int wid  = tid >> 6;
    int v = (tid < NB_SCAN) ? blksum[tid] : 0;
    int s = v;
#pragma unroll
    for (int off = 1; off < 64; off <<= 1) {
        int t = __shfl_up(s, off, 64);
        if (lane >= off) s += t;
    }
    if (wid == 0 && lane == 63) w0sum = s;
    __syncthreads();
    int excl = (s - v) + (wid ? w0sum : 0);
    if (tid < NB_SCAN) blksum[tid] = excl;
}

// ---------------------------------------------------------------------------
// K5: rowptr[i] = local[i] + blksum[block(i)]; cursor[i] = rowptr[i]
// ---------------------------------------------------------------------------
__global__ __launch_bounds__(256) void finalize_rowptr_kernel(const int* __restrict__ local,
                                                              const int* __restrict__ blksum,
                                                              int* __restrict__ rowptr,
                                                              int* __restrict__ cursor) {
    int i = blockIdx.x * 256 + threadIdx.x;
    if (i < N_NODES) {
        int v = local[i] + blksum[i >> 10];
        rowptr[i] = v;
        cursor[i] = v;
    }
}

// ---------------------------------------------------------------------------
// K6: bucket fill — sorted_src[cursor[dst[e]]++] = src[e]
// ---------------------------------------------------------------------------
__global__ __launch_bounds__(256) void fill_kernel(const int* __restrict__ src,
                                                   const int* __restrict__ dst,
                                                   int* __restrict__ cursor,
                                                   int* __restrict__ sorted_src) {
    int e = blockIdx.x * 256 + threadIdx.x;
    if (e < N_EDGES) {
        int d = dst[e];
        int pos = atomicAdd(&cursor[d], 1);
        sorted_src[pos] = src[e];
    }
}

// ---------------------------------------------------------------------------
// K7: zp[i][c] = rsqrt(deg[i]) * sum_k x[i][k]*W[c][k]
//     32 rows/block. x tile + W staged in LDS (dense coalesced float4).
//     W rows padded to 132 floats -> 16B-aligned float4 LDS reads.
// ---------------------------------------------------------------------------
__global__ __launch_bounds__(256) void gemm_kernel(const float* __restrict__ x,
                                                   const float* __restrict__ W,
                                                   const int* __restrict__ deg,
                                                   float* __restrict__ zp) {
    __shared__ float Ws[N_CLASSES * 132];
    __shared__ float Xs[32 * D_FEAT];
    const int tid = threadIdx.x;

    for (int i = tid; i < N_CLASSES * D_FEAT; i += 256)
        Ws[(i >> 7) * 132 + (i & 127)] = W[i];

    const float4* __restrict__ x4 = (const float4*)(x + (size_t)blockIdx.x * 32 * D_FEAT);
    float4* Xs4 = (float4*)Xs;
    for (int i = tid; i < 32 * (D_FEAT / 4); i += 256)
        Xs4[i] = x4[i];
    __syncthreads();

    const int c  = tid & 63;
    const int w  = tid >> 6;
    const int rb = w * 8;
    float acc[8] = {0.f, 0.f, 0.f, 0.f, 0.f, 0.f, 0.f, 0.f};

#pragma unroll 4
    for (int k4 = 0; k4 < D_FEAT / 4; k4++) {
        float4 wv = *(const float4*)&Ws[c * 132 + k4 * 4];
#pragma unroll
        for (int r = 0; r < 8; r++) {
            float4 xv = *(const float4*)&Xs[(rb + r) * D_FEAT + k4 * 4];
            acc[r] += xv.x * wv.x;
            acc[r] += xv.y * wv.y;
            acc[r] += xv.z * wv.z;
            acc[r] += xv.w * wv.w;
        }
    }

    const int row0 = blockIdx.x * 32 + rb;
#pragma unroll
    for (int r = 0; r < 8; r++) {
        int row = row0 + r;
        float dinv = rsqrtf((float)deg[row]);
        zp[row * N_CLASSES + c] = acc[r] * dinv;
    }
}

// ---------------------------------------------------------------------------
// K8: pull + fused bias/log-softmax. One wave per node, lane = class.
//     acc = zp[i] (self loop) + sum over in-edges of zp[src].
//     out[i] = log_softmax(acc * dinv[i] + b)
// ---------------------------------------------------------------------------
__global__ __launch_bounds__(256) void pull_kernel(const int* __restrict__ deg,
                                                   const int* __restrict__ rowptr,
                                                   const int* __restrict__ sorted_src,
                                                   const float* __restrict__ zp,
                                                   const float* __restrict__ b,
                                                   float* __restrict__ out) {
    const int node = blockIdx.x * 4 + (threadIdx.x >> 6);
    const int c    = threadIdx.x & 63;
    const int dg   = deg[node];
    const int cnt  = dg - 1;
    const int start = rowptr[node];

    float acc = zp[node * N_CLASSES + c];   // self-loop term

    for (int base = 0; base < cnt; base += 64) {
        int n = min(cnt - base, 64);
        int sidx = (c < n) ? sorted_src[start + base + c] : 0;
        int j = 0;
        for (; j + 4 <= n; j += 4) {
            int s0 = __shfl(sidx, j,     64);
            int s1 = __shfl(sidx, j + 1, 64);
            int s2 = __shfl(sidx, j + 2, 64);
            int s3 = __shfl(sidx, j + 3, 64);
            float v0 = zp[s0 * N_CLASSES + c];
            float v1 = zp[s1 * N_CLASSES + c];
            float v2 = zp[s2 * N_CLASSES + c];
            float v3 = zp[s3 * N_CLASSES + c];
            acc += v0; acc += v1; acc += v2; acc += v3;
        }
        for (; j < n; j++) {
            int s0 = __shfl(sidx, j, 64);
            acc += zp[s0 * N_CLASSES + c];
        }
    }

    float dinv = rsqrtf((float)dg);
    float v = acc * dinv + b[c];

    float m = v;
#pragma unroll
    for (int off = 32; off > 0; off >>= 1)
        m = fmaxf(m, __shfl_xor(m, off, 64));
    float ex = __expf(v - m);
    float l = ex;
#pragma unroll
    for (int off = 32; off > 0; off >>= 1)
        l += __shfl_xor(l, off, 64);

    out[node * N_CLASSES + c] = v - m - __logf(l);
}

// ---------------------------------------------------------------------------
// Launch
// ---------------------------------------------------------------------------
extern "C" void kernel_launch(void* const* d_in, const int* in_sizes, int n_in,
                              void* d_out, int out_size, void* d_ws, size_t ws_size,
                              hipStream_t stream) {
    const float* x    = (const float*)d_in[0];
    const int*   edge = (const int*)d_in[1];   // [2,E]: src then dst
    const float* W    = (const float*)d_in[2];
    const float* b    = (const float*)d_in[3];
    float* out = (float*)d_out;

    char* ws = (char*)d_ws;
    int*   deg    = (int*)(ws);                              // 400,000 B
    int*   local  = (int*)(ws + 512 * 1024);                 // 400,000 B
    int*   blksum = (int*)(ws + 1024 * 1024);                // 392 B
    int*   rowptr = (int*)(ws + 1024 * 1024 + 4096);         // 400,000 B
    int*   cursor = (int*)(ws + 1536 * 1024 + 4096);         // 400,000 B
    int*   ssrc   = (int*)(ws + 2 * 1024 * 1024);            // 6,400,000 B
    float* zp     = (float*)(ws + 9 * 1024 * 1024);          // 25,600,000 B

    const int* srcv = edge;
    const int* dstv = edge + N_EDGES;

    init_deg_kernel<<<(N_NODES + 255) / 256, 256, 0, stream>>>(deg);
    count_deg_kernel<<<(N_EDGES + 255) / 256, 256, 0, stream>>>(dstv, deg);
    scan_block_kernel<<<NB_SCAN, 1024, 0, stream>>>(deg, local, blksum);
    scan_tops_kernel<<<1, 128, 0, stream>>>(blksum);
    finalize_rowptr_kernel<<<(N_NODES + 255) / 256, 256, 0, stream>>>(local, blksum, rowptr, cursor);
    fill_kernel<<<(N_EDGES + 255) / 256, 256, 0, stream>>>(srcv, dstv, cursor, ssrc);
    gemm_kernel<<<N_NODES / 32, 256, 0, stream>>>(x, W, deg, zp);
    pull_kernel<<<N_NODES / 4, 256, 0, stream>>>(deg, rowptr, ssrc, zp, b, out);
}